// Round 19
// baseline (1337.024 us; speedup 1.0000x reference)
//
#include <hip/hip_runtime.h>

#define NN 40000
#define NNP 40064
#define NE 320000
#define DD 128
#define PP 16
#define FIN 64
#define NL 3
#define NG 40

typedef float4 f4;
typedef __attribute__((ext_vector_type(4))) float f32x4;
typedef _Float16 hf;
typedef __attribute__((ext_vector_type(4))) _Float16 h4;
typedef __attribute__((ext_vector_type(8))) _Float16 h8;

// ---------------- device-global scratch ----------------
__device__ hf    g_e   [NE * DD];          // edge state fp16 (CSR order)
__device__ hf    g_heta[NE * DD];          // hat_eta fp16
__device__ float g_h   [NNP * DD], g_p [NNP * DD];    // f32 masters
__device__ hf    g_h16 [NNP * DD], g_pf [NNP * DD];   // fp16 operand copies
__device__ float g_A1h [NNP * DD], g_C1p[NNP * DD];   // f32 (BN/readout path)
__device__ hf    g_A2h [NNP * DD], g_B1h[NNP * DD], g_B2h[NNP * DD], g_C2p[NNP * DD];
__device__ float g_st  [768];                          // hst | estA | estB
__device__ float g_p16 [NN * PP], g_psum[NG * PP], g_pss[NG * PP];
__device__ int   g_cum [64];
__device__ int   g_deg[NN], g_rowptr[NN + 1], g_cursor[NN], g_perm[NE], g_ssrc[NE], g_sdst[NE];
// transposed fp16 weights: [which][l][n][k]
__device__ hf    g_WA[2 * NL * DD * 256];
__device__ hf    g_WB[5 * NL * DD * DD];

__device__ __forceinline__ float sigm(float x) { return 1.0f / (1.0f + __expf(-x)); }

__global__ void k_zero(float* __restrict__ p, int n4)
{
    int i = blockIdx.x * 256 + threadIdx.x;
    if (i < n4) ((f4*)p)[i] = f4{0.f, 0.f, 0.f, 0.f};
}

__global__ void k_zeroi(int* __restrict__ p, int n)
{
    int i = blockIdx.x * 256 + threadIdx.x;
    if (i < n) p[i] = 0;
}

// ---------------- CSR build ----------------
__global__ void k_deg(const int* __restrict__ dst, int* __restrict__ deg)
{
    int e = blockIdx.x * 256 + threadIdx.x;
    if (e < NE) atomicAdd(&deg[dst[e]], 1);
}

__global__ __launch_bounds__(1024)
void k_scan(const int* __restrict__ deg, int* __restrict__ rowptr, int* __restrict__ cursor)
{
    __shared__ int sums[1024];
    int t = threadIdx.x;
    const int chunk = (NN + 1023) / 1024;
    int base = t * chunk;
    int s = 0;
    for (int i = 0; i < chunk; ++i) { int idx = base + i; if (idx < NN) s += deg[idx]; }
    sums[t] = s;
    __syncthreads();
    for (int off = 1; off < 1024; off <<= 1) {
        int v = (t >= off) ? sums[t - off] : 0;
        __syncthreads();
        sums[t] += v;
        __syncthreads();
    }
    int run = (t == 0) ? 0 : sums[t - 1];
    for (int i = 0; i < chunk; ++i) {
        int idx = base + i;
        if (idx < NN) { rowptr[idx] = run; cursor[idx] = run; run += deg[idx]; }
    }
    if (t == 1023) rowptr[NN] = sums[1023];
}

__global__ void k_fill(const int* __restrict__ dst, int* __restrict__ cursor,
                       int* __restrict__ perm)
{
    int e = blockIdx.x * 256 + threadIdx.x;
    if (e < NE) {
        int pos = atomicAdd(&cursor[dst[e]], 1);
        perm[pos] = e;
    }
}

__global__ void k_sortidx(const int* __restrict__ perm, const int* __restrict__ src,
                          const int* __restrict__ dst, int* __restrict__ ssrc,
                          int* __restrict__ sdst)
{
    int i = blockIdx.x * 256 + threadIdx.x;
    if (i < NE) { int e = perm[i]; ssrc[i] = src[e]; sdst[i] = dst[e]; }
}

// ---------------- weight prep: transpose to fp16 [n][k] ----------------
__global__ void k_wprepA(const float* __restrict__ A1W, const float* __restrict__ A2W,
                         hf* __restrict__ outh)
{
    int which = blockIdx.z, l = blockIdx.y;
    int idx = blockIdx.x * 256 + threadIdx.x;
    int k = idx >> 7, n = idx & 127;
    const float* W = (which == 0 ? A1W : A2W) + (size_t)l * 256 * 128;
    outh[((size_t)which * NL + l) * DD * 256 + (size_t)n * 256 + k] = (hf)W[k * 128 + n];
}

__global__ void k_wprepB(const float* __restrict__ B1W, const float* __restrict__ B2W,
                         const float* __restrict__ B3W, const float* __restrict__ C1W,
                         const float* __restrict__ C2W, hf* __restrict__ outh)
{
    int which = blockIdx.z, l = blockIdx.y;
    int idx = blockIdx.x * 256 + threadIdx.x;
    int k = idx >> 7, n = idx & 127;
    const float* W;
    switch (which) { case 0: W = B1W; break; case 1: W = B2W; break;
                     case 2: W = B3W; break; case 3: W = C1W; break; default: W = C2W; }
    W += (size_t)l * 128 * 128;
    outh[((size_t)which * NL + l) * DD * DD + (size_t)n * 128 + k] = (hf)W[k * 128 + n];
}

// ---------------- f32 GEMM (input projections; K=64/16); writes f32 + fp16 copy ------
template<int K>
__global__ __launch_bounds__(256)
void k_gemmF(const float* __restrict__ A, const float* __restrict__ W,
             const float* __restrict__ bias, float* __restrict__ C,
             hf* __restrict__ C16)
{
    __shared__ float As[64][20];
    __shared__ float Ws[16][128];
    const int tid = threadIdx.x;
    const int m0 = blockIdx.x * 64;
    const int ti = tid >> 4;
    const int tj = tid & 15;
    float acc[4][8];
    {
        float bv[8];
        #pragma unroll
        for (int c = 0; c < 8; ++c) bv[c] = bias[tj * 8 + c];
        #pragma unroll
        for (int r = 0; r < 4; ++r)
            #pragma unroll
            for (int c = 0; c < 8; ++c) acc[r][c] = bv[c];
    }
    const int ar = tid >> 2;
    const int ac = (tid & 3) * 4;
    for (int k0 = 0; k0 < K; k0 += 16) {
        f4 av = *(const f4*)(A + (size_t)(m0 + ar) * K + k0 + ac);
        *(f4*)&As[ar][ac] = av;
        {
            int q = tid;   int kr = q >> 5, c4 = (q & 31) * 4;
            *(f4*)&Ws[kr][c4] = *(const f4*)(W + (size_t)(k0 + kr) * 128 + c4);
            q = tid + 256; kr = q >> 5; c4 = (q & 31) * 4;
            *(f4*)&Ws[kr][c4] = *(const f4*)(W + (size_t)(k0 + kr) * 128 + c4);
        }
        __syncthreads();
        #pragma unroll
        for (int kk = 0; kk < 16; ++kk) {
            float a0 = As[ti * 4 + 0][kk];
            float a1 = As[ti * 4 + 1][kk];
            float a2 = As[ti * 4 + 2][kk];
            float a3 = As[ti * 4 + 3][kk];
            f4 w0 = *(f4*)&Ws[kk][tj * 8];
            f4 w1 = *(f4*)&Ws[kk][tj * 8 + 4];
            float wv[8] = {w0.x, w0.y, w0.z, w0.w, w1.x, w1.y, w1.z, w1.w};
            #pragma unroll
            for (int c = 0; c < 8; ++c) {
                acc[0][c] += a0 * wv[c];
                acc[1][c] += a1 * wv[c];
                acc[2][c] += a2 * wv[c];
                acc[3][c] += a3 * wv[c];
            }
        }
        __syncthreads();
    }
    #pragma unroll
    for (int r = 0; r < 4; ++r) {
        int row = m0 + ti * 4 + r;
        f4 o0 = {acc[r][0], acc[r][1], acc[r][2], acc[r][3]};
        f4 o1 = {acc[r][4], acc[r][5], acc[r][6], acc[r][7]};
        *(f4*)(C + (size_t)row * 128 + tj * 8)     = o0;
        *(f4*)(C + (size_t)row * 128 + tj * 8 + 4) = o1;
        h8 o16;
        #pragma unroll
        for (int c = 0; c < 8; ++c) o16[c] = (hf)acc[r][c];
        *(h8*)(C16 + (size_t)row * 128 + tj * 8) = o16;
    }
}

// ---------------- batched node fp16 MFMA GEMM (6 GEMMs / layer) ----------------
// blockIdx.y: 0=A1(f32) 1=A2(f16) [K=256, A=[h|p]] 2=B1 3=B2 [A=h] 4=C1(f32) 5=C2 [A=p]
struct NArgs {
    const hf* W[6];
    const float* bs[6];
    void* out[6];
};

__global__ __launch_bounds__(256)
void k_gemmN(NArgs a, const hf* __restrict__ hp, const hf* __restrict__ pp)
{
    __shared__ __align__(16) char smem[20480];
    hf (*As)[40] = (hf(*)[40])smem;              // 128x40x2 = 10240
    hf (*Wh)[40] = (hf(*)[40])(smem + 10240);    // 10240
    float* fstg = (float*)smem;                  // epilogue alias: 32x132x4 = 16896
    hf*    hstg = (hf*)smem;                     // epilogue alias: 32x136x2 = 8704
    const int tid = threadIdx.x;
    const int y = blockIdx.y;
    const int m0 = blockIdx.x * 128;
    const int K = (y < 2) ? 256 : 128;
    const hf* Wt = a.W[y];
    const int wid = tid >> 6, lane = tid & 63;
    const int lg = lane >> 4, ln = lane & 15;

    f32x4 acc[2][8];
    #pragma unroll
    for (int mt = 0; mt < 2; ++mt)
        #pragma unroll
        for (int nt = 0; nt < 8; ++nt) acc[mt][nt] = f32x4{0.f, 0.f, 0.f, 0.f};

    const int r1 = tid >> 2, g1 = (tid & 3) * 8;
    const int r2 = r1 + 64,  g2 = g1;

    for (int k0 = 0; k0 < K; k0 += 32) {
        const hf* pA; int kk;
        if (y < 2) {
            if (k0 >= 128) { pA = pp; kk = k0 - 128; }
            else           { pA = hp; kk = k0; }
        } else if (y < 4) { pA = hp; kk = k0; }
        else              { pA = pp; kk = k0; }
        *(f4*)&As[r1][g1] = *(const f4*)(pA + (size_t)(m0 + r1) * 128 + kk + g1);
        *(f4*)&As[r2][g2] = *(const f4*)(pA + (size_t)(m0 + r2) * 128 + kk + g2);
        *(f4*)&Wh[r1][g1] = *(const f4*)(Wt + (size_t)r1 * K + k0 + g1);
        *(f4*)&Wh[r2][g2] = *(const f4*)(Wt + (size_t)r2 * K + k0 + g2);
        __syncthreads();

        const int koff = lg * 8;
        h8 a0 = *(h8*)&As[wid * 32 + ln][koff];
        h8 a1 = *(h8*)&As[wid * 32 + 16 + ln][koff];
        #pragma unroll
        for (int nt = 0; nt < 8; ++nt) {
            h8 wh = *(h8*)&Wh[nt * 16 + ln][koff];
            acc[0][nt] = __builtin_amdgcn_mfma_f32_16x16x32_f16(a0, wh, acc[0][nt], 0, 0, 0);
            acc[1][nt] = __builtin_amdgcn_mfma_f32_16x16x32_f16(a1, wh, acc[1][nt], 0, 0, 0);
        }
        __syncthreads();
    }

    const float* bias = a.bs[y];
    const bool isF32 = (y == 0 || y == 4);
    if (isF32) {
        float* C = (float*)a.out[y];
        for (int pass = 0; pass < 4; ++pass) {
            if (wid == pass) {
                #pragma unroll
                for (int mt = 0; mt < 2; ++mt)
                    #pragma unroll
                    for (int nt = 0; nt < 8; ++nt)
                        #pragma unroll
                        for (int j = 0; j < 4; ++j)
                            fstg[(mt * 16 + lg * 4 + j) * 132 + nt * 16 + ln]
                                = acc[mt][nt][j] + bias[nt * 16 + ln];
            }
            __syncthreads();
            #pragma unroll
            for (int it = 0; it < 4; ++it) {
                int idx = it * 256 + tid;
                int r = idx >> 5, c4 = (idx & 31) * 4;
                *(f4*)(C + (size_t)(m0 + pass * 32 + r) * 128 + c4) = *(f4*)&fstg[r * 132 + c4];
            }
            __syncthreads();
        }
    } else {
        hf* C = (hf*)a.out[y];
        for (int pass = 0; pass < 4; ++pass) {
            if (wid == pass) {
                #pragma unroll
                for (int mt = 0; mt < 2; ++mt)
                    #pragma unroll
                    for (int nt = 0; nt < 8; ++nt)
                        #pragma unroll
                        for (int j = 0; j < 4; ++j)
                            hstg[(mt * 16 + lg * 4 + j) * 136 + nt * 16 + ln]
                                = (hf)(acc[mt][nt][j] + bias[nt * 16 + ln]);
            }
            __syncthreads();
            #pragma unroll
            for (int it = 0; it < 2; ++it) {
                int idx = it * 256 + tid;
                int r = idx >> 4, c8 = (idx & 15) * 8;
                *(f4*)(C + (size_t)(m0 + pass * 32 + r) * 128 + c8) = *(f4*)&hstg[r * 136 + c8];
            }
            __syncthreads();
        }
    }
}

// ---------------- edge fp16 MFMA GEMM (M-split 64 rows): heta = e@B3 + b3 + gathers --
// EUPD: A = e_old + relu(bn_prev(heta_prev)) in staging (wb: persist e_new).
// STATS: column stats of output -> st (shfl-reduced, 1 LDS atomic per col per wave).
template<bool EUPD, bool STATS>
__global__ __launch_bounds__(256)
void k_gemmE(hf* E, const hf* hetaPrev, hf* Cheta,
             const float* __restrict__ estPrev, const float* __restrict__ gamE,
             const float* __restrict__ betE,
             const hf* __restrict__ Wt,
             const float* __restrict__ bias,
             const hf* __restrict__ Gs, const hf* __restrict__ Gd,
             const int* __restrict__ srcI, const int* __restrict__ dstI,
             float* st, int wb)
{
    __shared__ __align__(16) char smem[15360];
    __shared__ float bnS[128], bnT[128];
    hf (*Ae)[40] = (hf(*)[40])smem;              // 64x40x2 = 5120
    hf (*Wh)[40] = (hf(*)[40])(smem + 5120);     // 128x40x2 = 10240
    float* sred = (float*)smem;                  // epilogue alias: 1024
    hf*    hstg = (hf*)(smem + 1024);            // epilogue alias: 16x136x2 = 4352
    const int tid = threadIdx.x;
    const int m0 = blockIdx.x * 64;
    const int wid = tid >> 6, lane = tid & 63;
    const int lg = lane >> 4, ln = lane & 15;

    if (EUPD) {
        if (tid < 128) {
            const float invME = 1.0f / NE;
            float m = estPrev[tid] * invME;
            float v = estPrev[128 + tid] * invME - m * m;
            float inv = 1.0f / sqrtf(v + 1e-5f);
            float gg = gamE[tid];
            bnS[tid] = gg * inv;
            bnT[tid] = betE[tid] - gg * m * inv;
        }
        __syncthreads();
    }

    f32x4 acc[8];
    #pragma unroll
    for (int nt = 0; nt < 8; ++nt) acc[nt] = f32x4{0.f, 0.f, 0.f, 0.f};

    const int r1 = tid >> 2, g1 = (tid & 3) * 8;   // A: 64 rows x 32 k, one h8/thread
    const int r2 = r1 + 64;                        // W: 128 rows x 32 k, two f4/thread

    for (int k0 = 0; k0 < 128; k0 += 32) {
        if (EUPD) {
            int row = m0 + r1, cb = k0 + g1;
            h8 ev = *(const h8*)(E + (size_t)row * 128 + cb);
            h8 tv = *(const h8*)(hetaPrev + (size_t)row * 128 + cb);
            h8 nv;
            #pragma unroll
            for (int j = 0; j < 8; ++j) {
                float xn = (float)tv[j] * bnS[cb + j] + bnT[cb + j];
                float en = (float)ev[j] + fmaxf(xn, 0.f);
                nv[j] = (hf)en;
            }
            *(h8*)&Ae[r1][g1] = nv;
            if (wb) *(h8*)(E + (size_t)row * 128 + cb) = nv;
        } else {
            *(f4*)&Ae[r1][g1] = *(const f4*)(E + (size_t)(m0 + r1) * 128 + k0 + g1);
        }
        *(f4*)&Wh[r1][g1] = *(const f4*)(Wt + (size_t)r1 * 128 + k0 + g1);
        *(f4*)&Wh[r2][g1] = *(const f4*)(Wt + (size_t)r2 * 128 + k0 + g1);
        __syncthreads();

        const int koff = lg * 8;
        h8 a0 = *(h8*)&Ae[wid * 16 + ln][koff];
        #pragma unroll
        for (int nt = 0; nt < 8; ++nt) {
            h8 wh = *(h8*)&Wh[nt * 16 + ln][koff];
            acc[nt] = __builtin_amdgcn_mfma_f32_16x16x32_f16(a0, wh, acc[nt], 0, 0, 0);
        }
        __syncthreads();
    }

    if (STATS) { sred[tid] = 0.f; __syncthreads(); }

    // bias + gathers into acc; stats
    {
        const int grow = m0 + wid * 16 + lg * 4;
        int sa[4], da[4];
        #pragma unroll
        for (int j = 0; j < 4; ++j) { sa[j] = srcI[grow + j]; da[j] = dstI[grow + j]; }
        #pragma unroll
        for (int nt = 0; nt < 8; ++nt) {
            const int col = nt * 16 + ln;
            const float b = bias[col];
            float ls = 0.f, lq = 0.f;
            #pragma unroll
            for (int j = 0; j < 4; ++j) {
                float x = acc[nt][j] + b
                        + (float)Gs[(size_t)sa[j] * 128 + col]
                        + (float)Gd[(size_t)da[j] * 128 + col];
                acc[nt][j] = x;
                if (STATS) { ls += x; lq += x * x; }
            }
            if (STATS) {
                ls += __shfl_xor(ls, 16); ls += __shfl_xor(ls, 32);
                lq += __shfl_xor(lq, 16); lq += __shfl_xor(lq, 32);
                if (lane < 16) {
                    atomicAdd(&sred[col], ls);
                    atomicAdd(&sred[128 + col], lq);
                }
            }
        }
    }

    // coalesced fp16 store via LDS staging (4 passes x 16 rows, padded rows)
    for (int pass = 0; pass < 4; ++pass) {
        if (wid == pass) {
            #pragma unroll
            for (int nt = 0; nt < 8; ++nt)
                #pragma unroll
                for (int j = 0; j < 4; ++j)
                    hstg[(lg * 4 + j) * 136 + nt * 16 + ln] = (hf)acc[nt][j];
        }
        __syncthreads();
        {
            int r = tid >> 4, c8 = (tid & 15) * 8;
            *(f4*)(Cheta + (size_t)(m0 + pass * 16 + r) * 128 + c8) = *(f4*)&hstg[r * 136 + c8];
        }
        __syncthreads();
    }
    if (STATS) atomicAdd(&st[tid], sred[tid]);
}

// ---------------- elementwise kernels ----------------

__global__ void k_einit(const float* __restrict__ ef, const int* __restrict__ perm,
                        const float* __restrict__ We, const float* __restrict__ be,
                        hf* __restrict__ E)
{
    size_t id = (size_t)blockIdx.x * 256 + threadIdx.x;
    int row = (int)(id >> 5);
    int c = (int)(id & 31) * 4;
    float s = ef[perm[row]];
    f4 w = *(const f4*)(We + c);
    f4 b = *(const f4*)(be + c);
    *(h4*)(E + (size_t)row * 128 + c)
        = h4{(hf)(s * w.x + b.x), (hf)(s * w.y + b.y), (hf)(s * w.z + b.z), (hf)(s * w.w + b.w)};
}

// ---------------- CSR node aggregation v2: 8 cols/thread, 2-edge unroll ----------------
__global__ void k_agg(const hf* __restrict__ heta, const hf* __restrict__ A2h,
                      const hf* __restrict__ C2p, const int* __restrict__ rowptr,
                      const int* __restrict__ ssrc, const float* __restrict__ snorm,
                      float* __restrict__ A1h, const float* __restrict__ C1p,
                      float* __restrict__ p, hf* __restrict__ pf,
                      float* __restrict__ st, int wp)
{
    int id = blockIdx.x * 256 + threadIdx.x;   // NN*16 total
    int row = id >> 4;
    int c = (id & 15) * 8;

    int s0 = rowptr[row], s1 = rowptr[row + 1];

    float ss[8], ah[8], cp[8];
    #pragma unroll
    for (int j = 0; j < 8; ++j) { ss[j] = 0.f; ah[j] = 0.f; cp[j] = 0.f; }

    int e = s0;
    for (; e + 1 < s1; e += 2) {
        int sA = ssrc[e], sB = ssrc[e + 1];
        h8 vA = *(const h8*)(heta + (size_t)e * 128 + c);
        h8 vB = *(const h8*)(heta + (size_t)(e + 1) * 128 + c);
        h8 aA = *(const h8*)(A2h + (size_t)sA * 128 + c);
        h8 aB = *(const h8*)(A2h + (size_t)sB * 128 + c);
        h8 cA = *(const h8*)(C2p + (size_t)sA * 128 + c);
        h8 cB = *(const h8*)(C2p + (size_t)sB * 128 + c);
        #pragma unroll
        for (int j = 0; j < 8; ++j) {
            float gA = sigm((float)vA[j]);
            float gB = sigm((float)vB[j]);
            ss[j] += gA + gB;
            ah[j] += gA * (float)aA[j] + gB * (float)aB[j];
            cp[j] += gA * (float)cA[j] + gB * (float)cB[j];
        }
    }
    if (e < s1) {
        int sA = ssrc[e];
        h8 vA = *(const h8*)(heta + (size_t)e * 128 + c);
        h8 aA = *(const h8*)(A2h + (size_t)sA * 128 + c);
        h8 cA = *(const h8*)(C2p + (size_t)sA * 128 + c);
        #pragma unroll
        for (int j = 0; j < 8; ++j) {
            float gA = sigm((float)vA[j]);
            ss[j] += gA;
            ah[j] += gA * (float)aA[j];
            cp[j] += gA * (float)cA[j];
        }
    }

    float hx[8];
    {
        float sn = snorm[row];
        f4 a1lo = *(const f4*)(A1h + (size_t)row * 128 + c);
        f4 a1hi = *(const f4*)(A1h + (size_t)row * 128 + c + 4);
        float a1[8] = {a1lo.x, a1lo.y, a1lo.z, a1lo.w, a1hi.x, a1hi.y, a1hi.z, a1hi.w};
        #pragma unroll
        for (int j = 0; j < 8; ++j) {
            float d = ss[j] + 1e-6f;
            hx[j] = (a1[j] + ah[j] / d) * sn;
            cp[j] = cp[j] / d;
        }
        f4 o0 = {hx[0], hx[1], hx[2], hx[3]};
        f4 o1 = {hx[4], hx[5], hx[6], hx[7]};
        *(f4*)(A1h + (size_t)row * 128 + c)     = o0;
        *(f4*)(A1h + (size_t)row * 128 + c + 4) = o1;
    }

    {
        f4 c1lo = *(const f4*)(C1p + (size_t)row * 128 + c);
        f4 c1hi = *(const f4*)(C1p + (size_t)row * 128 + c + 4);
        float c1[8] = {c1lo.x, c1lo.y, c1lo.z, c1lo.w, c1hi.x, c1hi.y, c1hi.z, c1hi.w};
        f4 pvlo = *(const f4*)(p + (size_t)row * 128 + c);
        f4 pvhi = *(const f4*)(p + (size_t)row * 128 + c + 4);
        float pv[8] = {pvlo.x, pvlo.y, pvlo.z, pvlo.w, pvhi.x, pvhi.y, pvhi.z, pvhi.w};
        #pragma unroll
        for (int j = 0; j < 8; ++j) pv[j] += tanhf(c1[j] + cp[j]);
        f4 o0 = {pv[0], pv[1], pv[2], pv[3]};
        f4 o1 = {pv[4], pv[5], pv[6], pv[7]};
        *(f4*)(p + (size_t)row * 128 + c)     = o0;
        *(f4*)(p + (size_t)row * 128 + c + 4) = o1;
        if (wp) {
            h8 ph;
            #pragma unroll
            for (int j = 0; j < 8; ++j) ph[j] = (hf)pv[j];
            *(h8*)(pf + (size_t)row * 128 + c) = ph;
        }
    }

    // column stats of hx -> st (h-path BN); block covers 16 nodes x 128 cols
    __shared__ float red[16][128];
    int lrow = threadIdx.x >> 4;
    #pragma unroll
    for (int j = 0; j < 8; ++j) red[lrow][c + j] = hx[j];
    __syncthreads();
    if (threadIdx.x < 128) {
        float a = 0.f;
        #pragma unroll
        for (int q = 0; q < 16; ++q) a += red[q][threadIdx.x];
        atomicAdd(&st[threadIdx.x], a);
    }
    __syncthreads();
    #pragma unroll
    for (int j = 0; j < 8; ++j) red[lrow][c + j] = hx[j] * hx[j];
    __syncthreads();
    if (threadIdx.x < 128) {
        float a = 0.f;
        #pragma unroll
        for (int q = 0; q < 16; ++q) a += red[q][threadIdx.x];
        atomicAdd(&st[128 + threadIdx.x], a);
    }
}

// h += relu(bn(X)); write h f32 + fp16 copy
__global__ void k_bnupd_h(float* __restrict__ Y, hf* __restrict__ Y16,
                          const float* __restrict__ X, const float* __restrict__ st,
                          const float* __restrict__ gam, const float* __restrict__ bet, float invM)
{
    size_t id = (size_t)blockIdx.x * 256 + threadIdx.x;
    int row = (int)(id >> 5);
    int c = (int)(id & 31) * 4;
    f4 x  = *(const f4*)(X + (size_t)row * 128 + c);
    f4 s  = *(const f4*)(st + c);
    f4 s2 = *(const f4*)(st + 128 + c);
    f4 g  = *(const f4*)(gam + c);
    f4 b  = *(const f4*)(bet + c);
    f4 y  = *(const f4*)(Y + (size_t)row * 128 + c);
    float m, v, o;
    m = s.x * invM; v = s2.x * invM - m * m; o = g.x * (x.x - m) / sqrtf(v + 1e-5f) + b.x; y.x += fmaxf(o, 0.f);
    m = s.y * invM; v = s2.y * invM - m * m; o = g.y * (x.y - m) / sqrtf(v + 1e-5f) + b.y; y.y += fmaxf(o, 0.f);
    m = s.z * invM; v = s2.z * invM - m * m; o = g.z * (x.z - m) / sqrtf(v + 1e-5f) + b.z; y.z += fmaxf(o, 0.f);
    m = s.w * invM; v = s2.w * invM - m * m; o = g.w * (x.w - m) / sqrtf(v + 1e-5f) + b.w; y.w += fmaxf(o, 0.f);
    *(f4*)(Y + (size_t)row * 128 + c) = y;
    *(h4*)(Y16 + (size_t)row * 128 + c) = h4{(hf)y.x, (hf)y.y, (hf)y.z, (hf)y.w};
}

// ---------------- readout ----------------

__global__ void k_p16(const float* __restrict__ p, const float* __restrict__ poutW,
                      const float* __restrict__ poutb, float* __restrict__ p16)
{
    int id = blockIdx.x * 256 + threadIdx.x;
    int i = id >> 4, c = id & 15;
    float a = poutb[c];
    for (int k = 0; k < 128; ++k) a += p[(size_t)i * 128 + k] * poutW[k * 16 + c];
    p16[id] = a;
}

__global__ void k_cum(const int* __restrict__ bnn, int* __restrict__ cum)
{
    if (threadIdx.x == 0) {
        cum[0] = 0;
        for (int g = 0; g < NG; ++g) cum[g + 1] = cum[g] + bnn[g];
    }
}

__global__ void k_graphstats(const float* __restrict__ p16, const int* __restrict__ cum,
                             float* __restrict__ psum, float* __restrict__ pss)
{
    int g = blockIdx.x;
    int t = threadIdx.x;
    int c = t & 15, s = t >> 4;
    int start = cum[g], end = cum[g + 1];
    float cnt = (float)(end - start);
    __shared__ float red[16][17];
    __shared__ float meanv[16];
    float loc = 0.f;
    for (int i = start + s; i < end; i += 16) loc += p16[(size_t)i * 16 + c];
    red[s][c] = loc;
    __syncthreads();
    if (s == 0) {
        float a = 0.f;
        #pragma unroll
        for (int q = 0; q < 16; ++q) a += red[q][c];
        psum[g * 16 + c] = a;
        meanv[c] = a / cnt;
    }
    __syncthreads();
    float m = meanv[c];
    loc = 0.f;
    for (int i = start + s; i < end; i += 16) {
        float v = p16[(size_t)i * 16 + c] - m;
        loc += v * v;
    }
    red[s][c] = loc;
    __syncthreads();
    if (s == 0) {
        float a = 0.f;
        #pragma unroll
        for (int q = 0; q < 16; ++q) a += red[q][c];
        pss[g * 16 + c] = a;
    }
}

__global__ void k_final(const float* __restrict__ h, const float* __restrict__ A1h,
                        const float* __restrict__ hst, const float* __restrict__ gam,
                        const float* __restrict__ bet,
                        const float* __restrict__ p16,
                        const float* __restrict__ psum, const float* __restrict__ pss,
                        const int* __restrict__ cum,
                        const float* __restrict__ WhpW, const float* __restrict__ Whpb,
                        const float* __restrict__ W0, const float* __restrict__ b0,
                        const float* __restrict__ W1, const float* __restrict__ b1,
                        const float* __restrict__ W2, const float* __restrict__ b2,
                        float* __restrict__ out)
{
    int g = blockIdx.x;
    int t = threadIdx.x;
    __shared__ float hpc[144];
    __shared__ float hpv[128];
    __shared__ float y0[64];
    __shared__ float y1[32];
    int fi = cum[g];
    float cnt = (float)(cum[g + 1] - cum[g]);
    {
        const float invM = 1.0f / NN;
        float m = hst[t] * invM;
        float v = hst[128 + t] * invM - m * m;
        float x = A1h[(size_t)fi * 128 + t];
        float o = gam[t] * (x - m) / sqrtf(v + 1e-5f) + bet[t];
        hpc[t] = h[(size_t)fi * 128 + t] + fmaxf(o, 0.f);
    }
    if (t < 16) {
        float centered = p16[(size_t)fi * 16 + t] - psum[g * 16 + t] / cnt;
        hpc[128 + t] = centered / sqrtf(pss[g * 16 + t]);
    }
    __syncthreads();
    float acc = Whpb[t];
    for (int k = 0; k < 144; ++k) acc += hpc[k] * WhpW[k * 128 + t];
    hpv[t] = acc;
    __syncthreads();
    if (t < 64) {
        float a = b0[t];
        for (int k = 0; k < 128; ++k) a += hpv[k] * W0[k * 64 + t];
        y0[t] = fmaxf(a, 0.f);
    }
    __syncthreads();
    if (t < 32) {
        float a = b1[t];
        for (int k = 0; k < 64; ++k) a += y0[k] * W1[k * 32 + t];
        y1[t] = fmaxf(a, 0.f);
    }
    __syncthreads();
    if (t == 0) {
        float a = b2[0];
        for (int k = 0; k < 32; ++k) a += y1[k] * W2[k];
        out[g] = a;
    }
}

// ---------------- host ----------------

extern "C" void kernel_launch(void* const* d_in, const int* in_sizes, int n_in,
                              void* d_out, int out_size, void* d_ws, size_t ws_size,
                              hipStream_t stream)
{
    (void)in_sizes; (void)n_in; (void)out_size; (void)d_ws; (void)ws_size;
    const float* node_feat = (const float*)d_in[0];
    const float* pos_enc   = (const float*)d_in[1];
    const float* edge_feat = (const float*)d_in[2];
    const float* snorm     = (const float*)d_in[3];
    const int*   src       = (const int*)d_in[4];
    const int*   dst       = (const int*)d_in[5];
    const int*   bnn       = (const int*)d_in[6];
    const float* W_h = (const float*)d_in[7],  *b_h = (const float*)d_in[8];
    const float* W_p = (const float*)d_in[9],  *b_p = (const float*)d_in[10];
    const float* W_e = (const float*)d_in[11], *b_e = (const float*)d_in[12];
    const float* A1W = (const float*)d_in[13], *A1b = (const float*)d_in[14];
    const float* A2W = (const float*)d_in[15], *A2b = (const float*)d_in[16];
    const float* B1W = (const float*)d_in[17], *B1b = (const float*)d_in[18];
    const float* B2W = (const float*)d_in[19], *B2b = (const float*)d_in[20];
    const float* B3W = (const float*)d_in[21], *B3b = (const float*)d_in[22];
    const float* C1W = (const float*)d_in[23], *C1b = (const float*)d_in[24];
    const float* C2W = (const float*)d_in[25], *C2b = (const float*)d_in[26];
    const float* bnhg = (const float*)d_in[27], *bnhb = (const float*)d_in[28];
    const float* bneg = (const float*)d_in[29], *bneb = (const float*)d_in[30];
    const float* poutW = (const float*)d_in[31], *poutb = (const float*)d_in[32];
    const float* WhpW = (const float*)d_in[33], *Whpb = (const float*)d_in[34];
    const float* W0 = (const float*)d_in[35], *b0 = (const float*)d_in[36];
    const float* W1 = (const float*)d_in[37], *b1 = (const float*)d_in[38];
    const float* W2 = (const float*)d_in[39], *b2 = (const float*)d_in[40];
    float* out = (float*)d_out;

    float *h, *p, *A1h, *C1p, *st, *p16, *psum, *pss;
    hf *e, *heta, *h16, *pf, *A2h, *B1h, *B2h, *C2p, *WA, *WB;
    int *cum, *deg, *rowptr, *cursor, *perm, *ssrc, *sdst;
    hipGetSymbolAddress((void**)&e,      HIP_SYMBOL(g_e));
    hipGetSymbolAddress((void**)&heta,   HIP_SYMBOL(g_heta));
    hipGetSymbolAddress((void**)&h,      HIP_SYMBOL(g_h));
    hipGetSymbolAddress((void**)&p,      HIP_SYMBOL(g_p));
    hipGetSymbolAddress((void**)&h16,    HIP_SYMBOL(g_h16));
    hipGetSymbolAddress((void**)&pf,     HIP_SYMBOL(g_pf));
    hipGetSymbolAddress((void**)&A1h,    HIP_SYMBOL(g_A1h));
    hipGetSymbolAddress((void**)&C1p,    HIP_SYMBOL(g_C1p));
    hipGetSymbolAddress((void**)&A2h,    HIP_SYMBOL(g_A2h));
    hipGetSymbolAddress((void**)&B1h,    HIP_SYMBOL(g_B1h));
    hipGetSymbolAddress((void**)&B2h,    HIP_SYMBOL(g_B2h));
    hipGetSymbolAddress((void**)&C2p,    HIP_SYMBOL(g_C2p));
    hipGetSymbolAddress((void**)&st,     HIP_SYMBOL(g_st));
    hipGetSymbolAddress((void**)&p16,    HIP_SYMBOL(g_p16));
    hipGetSymbolAddress((void**)&psum,   HIP_SYMBOL(g_psum));
    hipGetSymbolAddress((void**)&pss,    HIP_SYMBOL(g_pss));
    hipGetSymbolAddress((void**)&cum,    HIP_SYMBOL(g_cum));
    hipGetSymbolAddress((void**)&deg,    HIP_SYMBOL(g_deg));
    hipGetSymbolAddress((void**)&rowptr, HIP_SYMBOL(g_rowptr));
    hipGetSymbolAddress((void**)&cursor, HIP_SYMBOL(g_cursor));
    hipGetSymbolAddress((void**)&perm,   HIP_SYMBOL(g_perm));
    hipGetSymbolAddress((void**)&ssrc,   HIP_SYMBOL(g_ssrc));
    hipGetSymbolAddress((void**)&sdst,   HIP_SYMBOL(g_sdst));
    hipGetSymbolAddress((void**)&WA,     HIP_SYMBOL(g_WA));
    hipGetSymbolAddress((void**)&WB,     HIP_SYMBOL(g_WB));
    float* hst  = st;
    float* estA = st + 256;
    float* estB = st + 512;

    // ---- CSR build + weight prep ----
    k_zeroi<<<(NN + 255) / 256, 256, 0, stream>>>(deg, NN);
    k_deg<<<(NE + 255) / 256, 256, 0, stream>>>(dst, deg);
    k_scan<<<1, 1024, 0, stream>>>(deg, rowptr, cursor);
    k_fill<<<(NE + 255) / 256, 256, 0, stream>>>(dst, cursor, perm);
    k_sortidx<<<(NE + 255) / 256, 256, 0, stream>>>(perm, src, dst, ssrc, sdst);
    k_wprepA<<<dim3(128, NL, 2), 256, 0, stream>>>(A1W, A2W, WA);
    k_wprepB<<<dim3(64, NL, 5), 256, 0, stream>>>(B1W, B2W, B3W, C1W, C2W, WB);

    // ---- input projections (write f32 + fp16 copies directly) ----
    k_gemmF<FIN><<<NN / 64, 256, 0, stream>>>(node_feat, W_h, b_h, h, h16);
    k_gemmF<PP ><<<NN / 64, 256, 0, stream>>>(pos_enc,  W_p, b_p, p, pf);
    k_einit<<<NE * 32 / 256, 256, 0, stream>>>(edge_feat, perm, W_e, b_e, e);

    const int NB = NNP / 128;   // 313
    for (int l = 0; l < NL; ++l) {
        const hf* WB3 = WB + (size_t)(2 * NL + l) * DD * DD;

        NArgs na;
        na.W[0] = WA + (size_t)(0 * NL + l) * DD * 256;
        na.W[1] = WA + (size_t)(1 * NL + l) * DD * 256;
        na.W[2] = WB + (size_t)(0 * NL + l) * DD * DD;
        na.W[3] = WB + (size_t)(1 * NL + l) * DD * DD;
        na.W[4] = WB + (size_t)(3 * NL + l) * DD * DD;
        na.W[5] = WB + (size_t)(4 * NL + l) * DD * DD;
        na.bs[0] = A1b + l * DD; na.bs[1] = A2b + l * DD;
        na.bs[2] = B1b + l * DD; na.bs[3] = B2b + l * DD;
        na.bs[4] = C1b + l * DD; na.bs[5] = C2b + l * DD;
        na.out[0] = A1h; na.out[1] = A2h; na.out[2] = B1h;
        na.out[3] = B2h; na.out[4] = C1p; na.out[5] = C2p;
        k_gemmN<<<dim3(NB, 6), 256, 0, stream>>>(na, h16, pf);

        k_zero<<<1, 256, 0, stream>>>(hst, 64);

        if (l == 0) {
            k_zero<<<1, 256, 0, stream>>>(estA, 64);
            k_gemmE<false, true><<<NE / 64, 256, 0, stream>>>(
                e, nullptr, heta, nullptr, nullptr, nullptr,
                WB3, B3b + l * DD, B1h, B2h, ssrc, sdst, estA, 0);
        } else if (l == 1) {
            k_zero<<<1, 256, 0, stream>>>(estB, 64);
            k_gemmE<true, true><<<NE / 64, 256, 0, stream>>>(
                e, heta, heta, estA, bneg + 0 * DD, bneb + 0 * DD,
                WB3, B3b + l * DD, B1h, B2h, ssrc, sdst, estB, 1);
        } else {
            k_gemmE<true, false><<<NE / 64, 256, 0, stream>>>(
                e, heta, heta, estB, bneg + 1 * DD, bneb + 1 * DD,
                WB3, B3b + l * DD, B1h, B2h, ssrc, sdst, nullptr, 0);
        }

        k_agg<<<NN * 16 / 256, 256, 0, stream>>>(heta, A2h, C2p, rowptr, ssrc, snorm,
                                                 A1h, C1p, p, pf, hst,
                                                 (l < NL - 1) ? 1 : 0);

        if (l < NL - 1)
            k_bnupd_h<<<NN * 32 / 256, 256, 0, stream>>>(h, h16, A1h, hst,
                                                         bnhg + l * DD, bnhb + l * DD, 1.0f / NN);
    }

    // ---- readout ----
    k_p16<<<NN * 16 / 256, 256, 0, stream>>>(p, poutW, poutb, p16);
    k_cum<<<1, 64, 0, stream>>>(bnn, cum);
    k_graphstats<<<NG, 256, 0, stream>>>(p16, cum, psum, pss);
    k_final<<<NG, 128, 0, stream>>>(h, A1h, hst, bnhg + (NL - 1) * DD, bnhb + (NL - 1) * DD,
                                    p16, psum, pss, cum,
                                    WhpW, Whpb, W0, b0, W1, b1, W2, b2, out);
}

// Round 20
// 1052.411 us; speedup vs baseline: 1.2704x; 1.2704x over previous
//
#include <hip/hip_runtime.h>

#define NN 40000
#define NNP 40064
#define NE 320000
#define DD 128
#define PP 16
#define FIN 64
#define NL 3
#define NG 40

typedef float4 f4;
typedef __attribute__((ext_vector_type(4))) float f32x4;
typedef _Float16 hf;
typedef __attribute__((ext_vector_type(4))) _Float16 h4;
typedef __attribute__((ext_vector_type(8))) _Float16 h8;

// ---------------- device-global scratch ----------------
__device__ hf    g_e   [NE * DD];          // edge state fp16 (CSR order)
__device__ hf    g_heta[NE * DD];          // hat_eta fp16
__device__ float g_h   [NNP * DD], g_p [NNP * DD];    // f32 masters
__device__ hf    g_h16 [NNP * DD], g_pf [NNP * DD];   // fp16 operand copies
__device__ float g_A1h [NNP * DD], g_C1p[NNP * DD];   // f32 (BN/readout path)
__device__ hf    g_A2h [NNP * DD], g_B1h[NNP * DD], g_B2h[NNP * DD], g_C2p[NNP * DD];
__device__ float g_st  [768];                          // hst | estA | estB
__device__ float g_p16 [NN * PP], g_psum[NG * PP], g_pss[NG * PP];
__device__ int   g_cum [64];
__device__ int   g_deg[NN], g_rowptr[NN + 1], g_cursor[NN], g_perm[NE], g_ssrc[NE], g_sdst[NE];
// transposed fp16 weights: [which][l][n][k]
__device__ hf    g_WA[2 * NL * DD * 256];
__device__ hf    g_WB[5 * NL * DD * DD];

__device__ __forceinline__ float sigm(float x) { return 1.0f / (1.0f + __expf(-x)); }

__global__ void k_zero(float* __restrict__ p, int n4)
{
    int i = blockIdx.x * 256 + threadIdx.x;
    if (i < n4) ((f4*)p)[i] = f4{0.f, 0.f, 0.f, 0.f};
}

__global__ void k_zeroi(int* __restrict__ p, int n)
{
    int i = blockIdx.x * 256 + threadIdx.x;
    if (i < n) p[i] = 0;
}

// ---------------- CSR build ----------------
__global__ void k_deg(const int* __restrict__ dst, int* __restrict__ deg)
{
    int e = blockIdx.x * 256 + threadIdx.x;
    if (e < NE) atomicAdd(&deg[dst[e]], 1);
}

__global__ __launch_bounds__(1024)
void k_scan(const int* __restrict__ deg, int* __restrict__ rowptr, int* __restrict__ cursor)
{
    __shared__ int sums[1024];
    int t = threadIdx.x;
    const int chunk = (NN + 1023) / 1024;
    int base = t * chunk;
    int s = 0;
    for (int i = 0; i < chunk; ++i) { int idx = base + i; if (idx < NN) s += deg[idx]; }
    sums[t] = s;
    __syncthreads();
    for (int off = 1; off < 1024; off <<= 1) {
        int v = (t >= off) ? sums[t - off] : 0;
        __syncthreads();
        sums[t] += v;
        __syncthreads();
    }
    int run = (t == 0) ? 0 : sums[t - 1];
    for (int i = 0; i < chunk; ++i) {
        int idx = base + i;
        if (idx < NN) { rowptr[idx] = run; cursor[idx] = run; run += deg[idx]; }
    }
    if (t == 1023) rowptr[NN] = sums[1023];
}

__global__ void k_fill(const int* __restrict__ dst, int* __restrict__ cursor,
                       int* __restrict__ perm)
{
    int e = blockIdx.x * 256 + threadIdx.x;
    if (e < NE) {
        int pos = atomicAdd(&cursor[dst[e]], 1);
        perm[pos] = e;
    }
}

__global__ void k_sortidx(const int* __restrict__ perm, const int* __restrict__ src,
                          const int* __restrict__ dst, int* __restrict__ ssrc,
                          int* __restrict__ sdst)
{
    int i = blockIdx.x * 256 + threadIdx.x;
    if (i < NE) { int e = perm[i]; ssrc[i] = src[e]; sdst[i] = dst[e]; }
}

// ---------------- weight prep: transpose to fp16 [n][k] ----------------
__global__ void k_wprepA(const float* __restrict__ A1W, const float* __restrict__ A2W,
                         hf* __restrict__ outh)
{
    int which = blockIdx.z, l = blockIdx.y;
    int idx = blockIdx.x * 256 + threadIdx.x;
    int k = idx >> 7, n = idx & 127;
    const float* W = (which == 0 ? A1W : A2W) + (size_t)l * 256 * 128;
    outh[((size_t)which * NL + l) * DD * 256 + (size_t)n * 256 + k] = (hf)W[k * 128 + n];
}

__global__ void k_wprepB(const float* __restrict__ B1W, const float* __restrict__ B2W,
                         const float* __restrict__ B3W, const float* __restrict__ C1W,
                         const float* __restrict__ C2W, hf* __restrict__ outh)
{
    int which = blockIdx.z, l = blockIdx.y;
    int idx = blockIdx.x * 256 + threadIdx.x;
    int k = idx >> 7, n = idx & 127;
    const float* W;
    switch (which) { case 0: W = B1W; break; case 1: W = B2W; break;
                     case 2: W = B3W; break; case 3: W = C1W; break; default: W = C2W; }
    W += (size_t)l * 128 * 128;
    outh[((size_t)which * NL + l) * DD * DD + (size_t)n * 128 + k] = (hf)W[k * 128 + n];
}

// ---------------- f32 GEMM (input projections; K=64/16); writes f32 + fp16 copy ------
template<int K>
__global__ __launch_bounds__(256)
void k_gemmF(const float* __restrict__ A, const float* __restrict__ W,
             const float* __restrict__ bias, float* __restrict__ C,
             hf* __restrict__ C16)
{
    __shared__ float As[64][20];
    __shared__ float Ws[16][128];
    const int tid = threadIdx.x;
    const int m0 = blockIdx.x * 64;
    const int ti = tid >> 4;
    const int tj = tid & 15;
    float acc[4][8];
    {
        float bv[8];
        #pragma unroll
        for (int c = 0; c < 8; ++c) bv[c] = bias[tj * 8 + c];
        #pragma unroll
        for (int r = 0; r < 4; ++r)
            #pragma unroll
            for (int c = 0; c < 8; ++c) acc[r][c] = bv[c];
    }
    const int ar = tid >> 2;
    const int ac = (tid & 3) * 4;
    for (int k0 = 0; k0 < K; k0 += 16) {
        f4 av = *(const f4*)(A + (size_t)(m0 + ar) * K + k0 + ac);
        *(f4*)&As[ar][ac] = av;
        {
            int q = tid;   int kr = q >> 5, c4 = (q & 31) * 4;
            *(f4*)&Ws[kr][c4] = *(const f4*)(W + (size_t)(k0 + kr) * 128 + c4);
            q = tid + 256; kr = q >> 5; c4 = (q & 31) * 4;
            *(f4*)&Ws[kr][c4] = *(const f4*)(W + (size_t)(k0 + kr) * 128 + c4);
        }
        __syncthreads();
        #pragma unroll
        for (int kk = 0; kk < 16; ++kk) {
            float a0 = As[ti * 4 + 0][kk];
            float a1 = As[ti * 4 + 1][kk];
            float a2 = As[ti * 4 + 2][kk];
            float a3 = As[ti * 4 + 3][kk];
            f4 w0 = *(f4*)&Ws[kk][tj * 8];
            f4 w1 = *(f4*)&Ws[kk][tj * 8 + 4];
            float wv[8] = {w0.x, w0.y, w0.z, w0.w, w1.x, w1.y, w1.z, w1.w};
            #pragma unroll
            for (int c = 0; c < 8; ++c) {
                acc[0][c] += a0 * wv[c];
                acc[1][c] += a1 * wv[c];
                acc[2][c] += a2 * wv[c];
                acc[3][c] += a3 * wv[c];
            }
        }
        __syncthreads();
    }
    #pragma unroll
    for (int r = 0; r < 4; ++r) {
        int row = m0 + ti * 4 + r;
        f4 o0 = {acc[r][0], acc[r][1], acc[r][2], acc[r][3]};
        f4 o1 = {acc[r][4], acc[r][5], acc[r][6], acc[r][7]};
        *(f4*)(C + (size_t)row * 128 + tj * 8)     = o0;
        *(f4*)(C + (size_t)row * 128 + tj * 8 + 4) = o1;
        h8 o16;
        #pragma unroll
        for (int c = 0; c < 8; ++c) o16[c] = (hf)acc[r][c];
        *(h8*)(C16 + (size_t)row * 128 + tj * 8) = o16;
    }
}

// ---------------- batched node fp16 MFMA GEMM (6 GEMMs / layer) ----------------
// blockIdx.y: 0=A1(f32) 1=A2(f16) [K=256, A=[h|p]] 2=B1 3=B2 [A=h] 4=C1(f32) 5=C2 [A=p]
struct NArgs {
    const hf* W[6];
    const float* bs[6];
    void* out[6];
};

__global__ __launch_bounds__(256)
void k_gemmN(NArgs a, const hf* __restrict__ hp, const hf* __restrict__ pp)
{
    __shared__ __align__(16) char smem[20480];
    hf (*As)[40] = (hf(*)[40])smem;              // 128x40x2 = 10240
    hf (*Wh)[40] = (hf(*)[40])(smem + 10240);    // 10240
    float* fstg = (float*)smem;                  // epilogue alias: 32x132x4 = 16896
    hf*    hstg = (hf*)smem;                     // epilogue alias: 32x136x2 = 8704
    const int tid = threadIdx.x;
    const int y = blockIdx.y;
    const int m0 = blockIdx.x * 128;
    const int K = (y < 2) ? 256 : 128;
    const hf* Wt = a.W[y];
    const int wid = tid >> 6, lane = tid & 63;
    const int lg = lane >> 4, ln = lane & 15;

    f32x4 acc[2][8];
    #pragma unroll
    for (int mt = 0; mt < 2; ++mt)
        #pragma unroll
        for (int nt = 0; nt < 8; ++nt) acc[mt][nt] = f32x4{0.f, 0.f, 0.f, 0.f};

    const int r1 = tid >> 2, g1 = (tid & 3) * 8;
    const int r2 = r1 + 64,  g2 = g1;

    for (int k0 = 0; k0 < K; k0 += 32) {
        const hf* pA; int kk;
        if (y < 2) {
            if (k0 >= 128) { pA = pp; kk = k0 - 128; }
            else           { pA = hp; kk = k0; }
        } else if (y < 4) { pA = hp; kk = k0; }
        else              { pA = pp; kk = k0; }
        *(f4*)&As[r1][g1] = *(const f4*)(pA + (size_t)(m0 + r1) * 128 + kk + g1);
        *(f4*)&As[r2][g2] = *(const f4*)(pA + (size_t)(m0 + r2) * 128 + kk + g2);
        *(f4*)&Wh[r1][g1] = *(const f4*)(Wt + (size_t)r1 * K + k0 + g1);
        *(f4*)&Wh[r2][g2] = *(const f4*)(Wt + (size_t)r2 * K + k0 + g2);
        __syncthreads();

        const int koff = lg * 8;
        h8 a0 = *(h8*)&As[wid * 32 + ln][koff];
        h8 a1 = *(h8*)&As[wid * 32 + 16 + ln][koff];
        #pragma unroll
        for (int nt = 0; nt < 8; ++nt) {
            h8 wh = *(h8*)&Wh[nt * 16 + ln][koff];
            acc[0][nt] = __builtin_amdgcn_mfma_f32_16x16x32_f16(a0, wh, acc[0][nt], 0, 0, 0);
            acc[1][nt] = __builtin_amdgcn_mfma_f32_16x16x32_f16(a1, wh, acc[1][nt], 0, 0, 0);
        }
        __syncthreads();
    }

    const float* bias = a.bs[y];
    const bool isF32 = (y == 0 || y == 4);
    if (isF32) {
        float* C = (float*)a.out[y];
        for (int pass = 0; pass < 4; ++pass) {
            if (wid == pass) {
                #pragma unroll
                for (int mt = 0; mt < 2; ++mt)
                    #pragma unroll
                    for (int nt = 0; nt < 8; ++nt)
                        #pragma unroll
                        for (int j = 0; j < 4; ++j)
                            fstg[(mt * 16 + lg * 4 + j) * 132 + nt * 16 + ln]
                                = acc[mt][nt][j] + bias[nt * 16 + ln];
            }
            __syncthreads();
            #pragma unroll
            for (int it = 0; it < 4; ++it) {
                int idx = it * 256 + tid;
                int r = idx >> 5, c4 = (idx & 31) * 4;
                *(f4*)(C + (size_t)(m0 + pass * 32 + r) * 128 + c4) = *(f4*)&fstg[r * 132 + c4];
            }
            __syncthreads();
        }
    } else {
        hf* C = (hf*)a.out[y];
        for (int pass = 0; pass < 4; ++pass) {
            if (wid == pass) {
                #pragma unroll
                for (int mt = 0; mt < 2; ++mt)
                    #pragma unroll
                    for (int nt = 0; nt < 8; ++nt)
                        #pragma unroll
                        for (int j = 0; j < 4; ++j)
                            hstg[(mt * 16 + lg * 4 + j) * 136 + nt * 16 + ln]
                                = (hf)(acc[mt][nt][j] + bias[nt * 16 + ln]);
            }
            __syncthreads();
            #pragma unroll
            for (int it = 0; it < 2; ++it) {
                int idx = it * 256 + tid;
                int r = idx >> 4, c8 = (idx & 15) * 8;
                *(f4*)(C + (size_t)(m0 + pass * 32 + r) * 128 + c8) = *(f4*)&hstg[r * 136 + c8];
            }
            __syncthreads();
        }
    }
}

// ---------------- edge fp16 MFMA GEMM: heta = e@B3 + b3 + B1h[src] + B2h[dst] --------
// EUPD: A = e_old + relu(bn_prev(heta_prev)) in staging (wb: persist e_new).
// STATS: column stats of output -> st (shfl-reduced, 1 LDS atomic per col per wave).
template<bool EUPD, bool STATS>
__global__ __launch_bounds__(256)
void k_gemmE(hf* E, const hf* hetaPrev, hf* Cheta,
             const float* __restrict__ estPrev, const float* __restrict__ gamE,
             const float* __restrict__ betE,
             const hf* __restrict__ Wt,
             const float* __restrict__ bias,
             const hf* __restrict__ Gs, const hf* __restrict__ Gd,
             const int* __restrict__ srcI, const int* __restrict__ dstI,
             float* st, int wb)
{
    __shared__ __align__(16) char smem[20480];
    __shared__ float bnS[128], bnT[128];
    hf (*Ae)[40] = (hf(*)[40])smem;              // 10240
    hf (*Wh)[40] = (hf(*)[40])(smem + 10240);    // 10240
    float* sred = (float*)smem;                  // epilogue alias: 1024
    hf*    hstg = (hf*)(smem + 1024);            // epilogue alias: 32x136x2 = 8704
    const int tid = threadIdx.x;
    const int m0 = blockIdx.x * 128;
    const int wid = tid >> 6, lane = tid & 63;
    const int lg = lane >> 4, ln = lane & 15;

    if (EUPD) {
        if (tid < 128) {
            const float invME = 1.0f / NE;
            float m = estPrev[tid] * invME;
            float v = estPrev[128 + tid] * invME - m * m;
            float inv = 1.0f / sqrtf(v + 1e-5f);
            float gg = gamE[tid];
            bnS[tid] = gg * inv;
            bnT[tid] = betE[tid] - gg * m * inv;
        }
        __syncthreads();
    }

    f32x4 acc[2][8];
    #pragma unroll
    for (int mt = 0; mt < 2; ++mt)
        #pragma unroll
        for (int nt = 0; nt < 8; ++nt) acc[mt][nt] = f32x4{0.f, 0.f, 0.f, 0.f};

    const int r1 = tid >> 2, g1 = (tid & 3) * 8;
    const int r2 = r1 + 64,  g2 = g1;

    for (int k0 = 0; k0 < 128; k0 += 32) {
        if (EUPD) {
            #pragma unroll
            for (int half = 0; half < 2; ++half) {
                int r = half ? r2 : r1;
                int g = half ? g2 : g1;
                int row = m0 + r, cb = k0 + g;
                h8 ev = *(const h8*)(E + (size_t)row * 128 + cb);
                h8 tv = *(const h8*)(hetaPrev + (size_t)row * 128 + cb);
                h8 nv;
                #pragma unroll
                for (int j = 0; j < 8; ++j) {
                    float xn = (float)tv[j] * bnS[cb + j] + bnT[cb + j];
                    float en = (float)ev[j] + fmaxf(xn, 0.f);
                    nv[j] = (hf)en;
                }
                *(h8*)&Ae[r][g] = nv;
                if (wb) *(h8*)(E + (size_t)row * 128 + cb) = nv;
            }
        } else {
            *(f4*)&Ae[r1][g1] = *(const f4*)(E + (size_t)(m0 + r1) * 128 + k0 + g1);
            *(f4*)&Ae[r2][g2] = *(const f4*)(E + (size_t)(m0 + r2) * 128 + k0 + g2);
        }
        *(f4*)&Wh[r1][g1] = *(const f4*)(Wt + (size_t)r1 * 128 + k0 + g1);
        *(f4*)&Wh[r2][g2] = *(const f4*)(Wt + (size_t)r2 * 128 + k0 + g2);
        __syncthreads();

        const int koff = lg * 8;
        h8 a0 = *(h8*)&Ae[wid * 32 + ln][koff];
        h8 a1 = *(h8*)&Ae[wid * 32 + 16 + ln][koff];
        #pragma unroll
        for (int nt = 0; nt < 8; ++nt) {
            h8 wh = *(h8*)&Wh[nt * 16 + ln][koff];
            acc[0][nt] = __builtin_amdgcn_mfma_f32_16x16x32_f16(a0, wh, acc[0][nt], 0, 0, 0);
            acc[1][nt] = __builtin_amdgcn_mfma_f32_16x16x32_f16(a1, wh, acc[1][nt], 0, 0, 0);
        }
        __syncthreads();
    }

    if (STATS) { sred[tid] = 0.f; __syncthreads(); }

    // bias + gathers into acc; stats
    #pragma unroll
    for (int mt = 0; mt < 2; ++mt) {
        const int grow = m0 + wid * 32 + mt * 16 + lg * 4;
        int sa[4], da[4];
        #pragma unroll
        for (int j = 0; j < 4; ++j) { sa[j] = srcI[grow + j]; da[j] = dstI[grow + j]; }
        #pragma unroll
        for (int nt = 0; nt < 8; ++nt) {
            const int col = nt * 16 + ln;
            const float b = bias[col];
            float ls = 0.f, lq = 0.f;
            #pragma unroll
            for (int j = 0; j < 4; ++j) {
                float x = acc[mt][nt][j] + b
                        + (float)Gs[(size_t)sa[j] * 128 + col]
                        + (float)Gd[(size_t)da[j] * 128 + col];
                acc[mt][nt][j] = x;
                if (STATS) { ls += x; lq += x * x; }
            }
            if (STATS) {
                ls += __shfl_xor(ls, 16); ls += __shfl_xor(ls, 32);
                lq += __shfl_xor(lq, 16); lq += __shfl_xor(lq, 32);
                if (lane < 16) {
                    atomicAdd(&sred[col], ls);
                    atomicAdd(&sred[128 + col], lq);
                }
            }
        }
    }

    // coalesced fp16 store via LDS staging (4 passes x 32 rows, padded rows)
    for (int pass = 0; pass < 4; ++pass) {
        if (wid == pass) {
            #pragma unroll
            for (int mt = 0; mt < 2; ++mt)
                #pragma unroll
                for (int nt = 0; nt < 8; ++nt)
                    #pragma unroll
                    for (int j = 0; j < 4; ++j)
                        hstg[(mt * 16 + lg * 4 + j) * 136 + nt * 16 + ln]
                            = (hf)acc[mt][nt][j];
        }
        __syncthreads();
        #pragma unroll
        for (int it = 0; it < 2; ++it) {
            int idx = it * 256 + tid;
            int r = idx >> 4, c8 = (idx & 15) * 8;
            *(f4*)(Cheta + (size_t)(m0 + pass * 32 + r) * 128 + c8) = *(f4*)&hstg[r * 136 + c8];
        }
        __syncthreads();
    }
    if (STATS) atomicAdd(&st[tid], sred[tid]);
}

// ---------------- elementwise kernels ----------------

__global__ void k_einit(const float* __restrict__ ef, const int* __restrict__ perm,
                        const float* __restrict__ We, const float* __restrict__ be,
                        hf* __restrict__ E)
{
    size_t id = (size_t)blockIdx.x * 256 + threadIdx.x;
    int row = (int)(id >> 5);
    int c = (int)(id & 31) * 4;
    float s = ef[perm[row]];
    f4 w = *(const f4*)(We + c);
    f4 b = *(const f4*)(be + c);
    *(h4*)(E + (size_t)row * 128 + c)
        = h4{(hf)(s * w.x + b.x), (hf)(s * w.y + b.y), (hf)(s * w.z + b.z), (hf)(s * w.w + b.w)};
}

// ---------------- CSR node aggregation v2: 8 cols/thread, 2-edge unroll ----------------
__global__ void k_agg(const hf* __restrict__ heta, const hf* __restrict__ A2h,
                      const hf* __restrict__ C2p, const int* __restrict__ rowptr,
                      const int* __restrict__ ssrc, const float* __restrict__ snorm,
                      float* __restrict__ A1h, const float* __restrict__ C1p,
                      float* __restrict__ p, hf* __restrict__ pf,
                      float* __restrict__ st, int wp)
{
    int id = blockIdx.x * 256 + threadIdx.x;   // NN*16 total
    int row = id >> 4;
    int c = (id & 15) * 8;

    int s0 = rowptr[row], s1 = rowptr[row + 1];

    float ss[8], ah[8], cp[8];
    #pragma unroll
    for (int j = 0; j < 8; ++j) { ss[j] = 0.f; ah[j] = 0.f; cp[j] = 0.f; }

    int e = s0;
    for (; e + 1 < s1; e += 2) {
        int sA = ssrc[e], sB = ssrc[e + 1];
        h8 vA = *(const h8*)(heta + (size_t)e * 128 + c);
        h8 vB = *(const h8*)(heta + (size_t)(e + 1) * 128 + c);
        h8 aA = *(const h8*)(A2h + (size_t)sA * 128 + c);
        h8 aB = *(const h8*)(A2h + (size_t)sB * 128 + c);
        h8 cA = *(const h8*)(C2p + (size_t)sA * 128 + c);
        h8 cB = *(const h8*)(C2p + (size_t)sB * 128 + c);
        #pragma unroll
        for (int j = 0; j < 8; ++j) {
            float gA = sigm((float)vA[j]);
            float gB = sigm((float)vB[j]);
            ss[j] += gA + gB;
            ah[j] += gA * (float)aA[j] + gB * (float)aB[j];
            cp[j] += gA * (float)cA[j] + gB * (float)cB[j];
        }
    }
    if (e < s1) {
        int sA = ssrc[e];
        h8 vA = *(const h8*)(heta + (size_t)e * 128 + c);
        h8 aA = *(const h8*)(A2h + (size_t)sA * 128 + c);
        h8 cA = *(const h8*)(C2p + (size_t)sA * 128 + c);
        #pragma unroll
        for (int j = 0; j < 8; ++j) {
            float gA = sigm((float)vA[j]);
            ss[j] += gA;
            ah[j] += gA * (float)aA[j];
            cp[j] += gA * (float)cA[j];
        }
    }

    float hx[8];
    {
        float sn = snorm[row];
        f4 a1lo = *(const f4*)(A1h + (size_t)row * 128 + c);
        f4 a1hi = *(const f4*)(A1h + (size_t)row * 128 + c + 4);
        float a1[8] = {a1lo.x, a1lo.y, a1lo.z, a1lo.w, a1hi.x, a1hi.y, a1hi.z, a1hi.w};
        #pragma unroll
        for (int j = 0; j < 8; ++j) {
            float d = ss[j] + 1e-6f;
            hx[j] = (a1[j] + ah[j] / d) * sn;
            cp[j] = cp[j] / d;
        }
        f4 o0 = {hx[0], hx[1], hx[2], hx[3]};
        f4 o1 = {hx[4], hx[5], hx[6], hx[7]};
        *(f4*)(A1h + (size_t)row * 128 + c)     = o0;
        *(f4*)(A1h + (size_t)row * 128 + c + 4) = o1;
    }

    {
        f4 c1lo = *(const f4*)(C1p + (size_t)row * 128 + c);
        f4 c1hi = *(const f4*)(C1p + (size_t)row * 128 + c + 4);
        float c1[8] = {c1lo.x, c1lo.y, c1lo.z, c1lo.w, c1hi.x, c1hi.y, c1hi.z, c1hi.w};
        f4 pvlo = *(const f4*)(p + (size_t)row * 128 + c);
        f4 pvhi = *(const f4*)(p + (size_t)row * 128 + c + 4);
        float pv[8] = {pvlo.x, pvlo.y, pvlo.z, pvlo.w, pvhi.x, pvhi.y, pvhi.z, pvhi.w};
        #pragma unroll
        for (int j = 0; j < 8; ++j) pv[j] += tanhf(c1[j] + cp[j]);
        f4 o0 = {pv[0], pv[1], pv[2], pv[3]};
        f4 o1 = {pv[4], pv[5], pv[6], pv[7]};
        *(f4*)(p + (size_t)row * 128 + c)     = o0;
        *(f4*)(p + (size_t)row * 128 + c + 4) = o1;
        if (wp) {
            h8 ph;
            #pragma unroll
            for (int j = 0; j < 8; ++j) ph[j] = (hf)pv[j];
            *(h8*)(pf + (size_t)row * 128 + c) = ph;
        }
    }

    // column stats of hx -> st (h-path BN); block covers 16 nodes x 128 cols
    __shared__ float red[16][128];
    int lrow = threadIdx.x >> 4;
    #pragma unroll
    for (int j = 0; j < 8; ++j) red[lrow][c + j] = hx[j];
    __syncthreads();
    if (threadIdx.x < 128) {
        float a = 0.f;
        #pragma unroll
        for (int q = 0; q < 16; ++q) a += red[q][threadIdx.x];
        atomicAdd(&st[threadIdx.x], a);
    }
    __syncthreads();
    #pragma unroll
    for (int j = 0; j < 8; ++j) red[lrow][c + j] = hx[j] * hx[j];
    __syncthreads();
    if (threadIdx.x < 128) {
        float a = 0.f;
        #pragma unroll
        for (int q = 0; q < 16; ++q) a += red[q][threadIdx.x];
        atomicAdd(&st[128 + threadIdx.x], a);
    }
}

// h += relu(bn(X)); write h f32 + fp16 copy
__global__ void k_bnupd_h(float* __restrict__ Y, hf* __restrict__ Y16,
                          const float* __restrict__ X, const float* __restrict__ st,
                          const float* __restrict__ gam, const float* __restrict__ bet, float invM)
{
    size_t id = (size_t)blockIdx.x * 256 + threadIdx.x;
    int row = (int)(id >> 5);
    int c = (int)(id & 31) * 4;
    f4 x  = *(const f4*)(X + (size_t)row * 128 + c);
    f4 s  = *(const f4*)(st + c);
    f4 s2 = *(const f4*)(st + 128 + c);
    f4 g  = *(const f4*)(gam + c);
    f4 b  = *(const f4*)(bet + c);
    f4 y  = *(const f4*)(Y + (size_t)row * 128 + c);
    float m, v, o;
    m = s.x * invM; v = s2.x * invM - m * m; o = g.x * (x.x - m) / sqrtf(v + 1e-5f) + b.x; y.x += fmaxf(o, 0.f);
    m = s.y * invM; v = s2.y * invM - m * m; o = g.y * (x.y - m) / sqrtf(v + 1e-5f) + b.y; y.y += fmaxf(o, 0.f);
    m = s.z * invM; v = s2.z * invM - m * m; o = g.z * (x.z - m) / sqrtf(v + 1e-5f) + b.z; y.z += fmaxf(o, 0.f);
    m = s.w * invM; v = s2.w * invM - m * m; o = g.w * (x.w - m) / sqrtf(v + 1e-5f) + b.w; y.w += fmaxf(o, 0.f);
    *(f4*)(Y + (size_t)row * 128 + c) = y;
    *(h4*)(Y16 + (size_t)row * 128 + c) = h4{(hf)y.x, (hf)y.y, (hf)y.z, (hf)y.w};
}

// ---------------- readout ----------------

__global__ void k_p16(const float* __restrict__ p, const float* __restrict__ poutW,
                      const float* __restrict__ poutb, float* __restrict__ p16)
{
    int id = blockIdx.x * 256 + threadIdx.x;
    int i = id >> 4, c = id & 15;
    float a = poutb[c];
    for (int k = 0; k < 128; ++k) a += p[(size_t)i * 128 + k] * poutW[k * 16 + c];
    p16[id] = a;
}

__global__ void k_cum(const int* __restrict__ bnn, int* __restrict__ cum)
{
    if (threadIdx.x == 0) {
        cum[0] = 0;
        for (int g = 0; g < NG; ++g) cum[g + 1] = cum[g] + bnn[g];
    }
}

__global__ void k_graphstats(const float* __restrict__ p16, const int* __restrict__ cum,
                             float* __restrict__ psum, float* __restrict__ pss)
{
    int g = blockIdx.x;
    int t = threadIdx.x;
    int c = t & 15, s = t >> 4;
    int start = cum[g], end = cum[g + 1];
    float cnt = (float)(end - start);
    __shared__ float red[16][17];
    __shared__ float meanv[16];
    float loc = 0.f;
    for (int i = start + s; i < end; i += 16) loc += p16[(size_t)i * 16 + c];
    red[s][c] = loc;
    __syncthreads();
    if (s == 0) {
        float a = 0.f;
        #pragma unroll
        for (int q = 0; q < 16; ++q) a += red[q][c];
        psum[g * 16 + c] = a;
        meanv[c] = a / cnt;
    }
    __syncthreads();
    float m = meanv[c];
    loc = 0.f;
    for (int i = start + s; i < end; i += 16) {
        float v = p16[(size_t)i * 16 + c] - m;
        loc += v * v;
    }
    red[s][c] = loc;
    __syncthreads();
    if (s == 0) {
        float a = 0.f;
        #pragma unroll
        for (int q = 0; q < 16; ++q) a += red[q][c];
        pss[g * 16 + c] = a;
    }
}

__global__ void k_final(const float* __restrict__ h, const float* __restrict__ A1h,
                        const float* __restrict__ hst, const float* __restrict__ gam,
                        const float* __restrict__ bet,
                        const float* __restrict__ p16,
                        const float* __restrict__ psum, const float* __restrict__ pss,
                        const int* __restrict__ cum,
                        const float* __restrict__ WhpW, const float* __restrict__ Whpb,
                        const float* __restrict__ W0, const float* __restrict__ b0,
                        const float* __restrict__ W1, const float* __restrict__ b1,
                        const float* __restrict__ W2, const float* __restrict__ b2,
                        float* __restrict__ out)
{
    int g = blockIdx.x;
    int t = threadIdx.x;
    __shared__ float hpc[144];
    __shared__ float hpv[128];
    __shared__ float y0[64];
    __shared__ float y1[32];
    int fi = cum[g];
    float cnt = (float)(cum[g + 1] - cum[g]);
    {
        const float invM = 1.0f / NN;
        float m = hst[t] * invM;
        float v = hst[128 + t] * invM - m * m;
        float x = A1h[(size_t)fi * 128 + t];
        float o = gam[t] * (x - m) / sqrtf(v + 1e-5f) + bet[t];
        hpc[t] = h[(size_t)fi * 128 + t] + fmaxf(o, 0.f);
    }
    if (t < 16) {
        float centered = p16[(size_t)fi * 16 + t] - psum[g * 16 + t] / cnt;
        hpc[128 + t] = centered / sqrtf(pss[g * 16 + t]);
    }
    __syncthreads();
    float acc = Whpb[t];
    for (int k = 0; k < 144; ++k) acc += hpc[k] * WhpW[k * 128 + t];
    hpv[t] = acc;
    __syncthreads();
    if (t < 64) {
        float a = b0[t];
        for (int k = 0; k < 128; ++k) a += hpv[k] * W0[k * 64 + t];
        y0[t] = fmaxf(a, 0.f);
    }
    __syncthreads();
    if (t < 32) {
        float a = b1[t];
        for (int k = 0; k < 64; ++k) a += y0[k] * W1[k * 32 + t];
        y1[t] = fmaxf(a, 0.f);
    }
    __syncthreads();
    if (t == 0) {
        float a = b2[0];
        for (int k = 0; k < 32; ++k) a += y1[k] * W2[k];
        out[g] = a;
    }
}

// ---------------- host ----------------

extern "C" void kernel_launch(void* const* d_in, const int* in_sizes, int n_in,
                              void* d_out, int out_size, void* d_ws, size_t ws_size,
                              hipStream_t stream)
{
    (void)in_sizes; (void)n_in; (void)out_size; (void)d_ws; (void)ws_size;
    const float* node_feat = (const float*)d_in[0];
    const float* pos_enc   = (const float*)d_in[1];
    const float* edge_feat = (const float*)d_in[2];
    const float* snorm     = (const float*)d_in[3];
    const int*   src       = (const int*)d_in[4];
    const int*   dst       = (const int*)d_in[5];
    const int*   bnn       = (const int*)d_in[6];
    const float* W_h = (const float*)d_in[7],  *b_h = (const float*)d_in[8];
    const float* W_p = (const float*)d_in[9],  *b_p = (const float*)d_in[10];
    const float* W_e = (const float*)d_in[11], *b_e = (const float*)d_in[12];
    const float* A1W = (const float*)d_in[13], *A1b = (const float*)d_in[14];
    const float* A2W = (const float*)d_in[15], *A2b = (const float*)d_in[16];
    const float* B1W = (const float*)d_in[17], *B1b = (const float*)d_in[18];
    const float* B2W = (const float*)d_in[19], *B2b = (const float*)d_in[20];
    const float* B3W = (const float*)d_in[21], *B3b = (const float*)d_in[22];
    const float* C1W = (const float*)d_in[23], *C1b = (const float*)d_in[24];
    const float* C2W = (const float*)d_in[25], *C2b = (const float*)d_in[26];
    const float* bnhg = (const float*)d_in[27], *bnhb = (const float*)d_in[28];
    const float* bneg = (const float*)d_in[29], *bneb = (const float*)d_in[30];
    const float* poutW = (const float*)d_in[31], *poutb = (const float*)d_in[32];
    const float* WhpW = (const float*)d_in[33], *Whpb = (const float*)d_in[34];
    const float* W0 = (const float*)d_in[35], *b0 = (const float*)d_in[36];
    const float* W1 = (const float*)d_in[37], *b1 = (const float*)d_in[38];
    const float* W2 = (const float*)d_in[39], *b2 = (const float*)d_in[40];
    float* out = (float*)d_out;

    float *h, *p, *A1h, *C1p, *st, *p16, *psum, *pss;
    hf *e, *heta, *h16, *pf, *A2h, *B1h, *B2h, *C2p, *WA, *WB;
    int *cum, *deg, *rowptr, *cursor, *perm, *ssrc, *sdst;
    hipGetSymbolAddress((void**)&e,      HIP_SYMBOL(g_e));
    hipGetSymbolAddress((void**)&heta,   HIP_SYMBOL(g_heta));
    hipGetSymbolAddress((void**)&h,      HIP_SYMBOL(g_h));
    hipGetSymbolAddress((void**)&p,      HIP_SYMBOL(g_p));
    hipGetSymbolAddress((void**)&h16,    HIP_SYMBOL(g_h16));
    hipGetSymbolAddress((void**)&pf,     HIP_SYMBOL(g_pf));
    hipGetSymbolAddress((void**)&A1h,    HIP_SYMBOL(g_A1h));
    hipGetSymbolAddress((void**)&C1p,    HIP_SYMBOL(g_C1p));
    hipGetSymbolAddress((void**)&A2h,    HIP_SYMBOL(g_A2h));
    hipGetSymbolAddress((void**)&B1h,    HIP_SYMBOL(g_B1h));
    hipGetSymbolAddress((void**)&B2h,    HIP_SYMBOL(g_B2h));
    hipGetSymbolAddress((void**)&C2p,    HIP_SYMBOL(g_C2p));
    hipGetSymbolAddress((void**)&st,     HIP_SYMBOL(g_st));
    hipGetSymbolAddress((void**)&p16,    HIP_SYMBOL(g_p16));
    hipGetSymbolAddress((void**)&psum,   HIP_SYMBOL(g_psum));
    hipGetSymbolAddress((void**)&pss,    HIP_SYMBOL(g_pss));
    hipGetSymbolAddress((void**)&cum,    HIP_SYMBOL(g_cum));
    hipGetSymbolAddress((void**)&deg,    HIP_SYMBOL(g_deg));
    hipGetSymbolAddress((void**)&rowptr, HIP_SYMBOL(g_rowptr));
    hipGetSymbolAddress((void**)&cursor, HIP_SYMBOL(g_cursor));
    hipGetSymbolAddress((void**)&perm,   HIP_SYMBOL(g_perm));
    hipGetSymbolAddress((void**)&ssrc,   HIP_SYMBOL(g_ssrc));
    hipGetSymbolAddress((void**)&sdst,   HIP_SYMBOL(g_sdst));
    hipGetSymbolAddress((void**)&WA,     HIP_SYMBOL(g_WA));
    hipGetSymbolAddress((void**)&WB,     HIP_SYMBOL(g_WB));
    float* hst  = st;
    float* estA = st + 256;
    float* estB = st + 512;

    // ---- CSR build + weight prep ----
    k_zeroi<<<(NN + 255) / 256, 256, 0, stream>>>(deg, NN);
    k_deg<<<(NE + 255) / 256, 256, 0, stream>>>(dst, deg);
    k_scan<<<1, 1024, 0, stream>>>(deg, rowptr, cursor);
    k_fill<<<(NE + 255) / 256, 256, 0, stream>>>(dst, cursor, perm);
    k_sortidx<<<(NE + 255) / 256, 256, 0, stream>>>(perm, src, dst, ssrc, sdst);
    k_wprepA<<<dim3(128, NL, 2), 256, 0, stream>>>(A1W, A2W, WA);
    k_wprepB<<<dim3(64, NL, 5), 256, 0, stream>>>(B1W, B2W, B3W, C1W, C2W, WB);

    // ---- input projections (write f32 + fp16 copies directly) ----
    k_gemmF<FIN><<<NN / 64, 256, 0, stream>>>(node_feat, W_h, b_h, h, h16);
    k_gemmF<PP ><<<NN / 64, 256, 0, stream>>>(pos_enc,  W_p, b_p, p, pf);
    k_einit<<<NE * 32 / 256, 256, 0, stream>>>(edge_feat, perm, W_e, b_e, e);

    const int NB = NNP / 128;   // 313
    for (int l = 0; l < NL; ++l) {
        const hf* WB3 = WB + (size_t)(2 * NL + l) * DD * DD;

        NArgs na;
        na.W[0] = WA + (size_t)(0 * NL + l) * DD * 256;
        na.W[1] = WA + (size_t)(1 * NL + l) * DD * 256;
        na.W[2] = WB + (size_t)(0 * NL + l) * DD * DD;
        na.W[3] = WB + (size_t)(1 * NL + l) * DD * DD;
        na.W[4] = WB + (size_t)(3 * NL + l) * DD * DD;
        na.W[5] = WB + (size_t)(4 * NL + l) * DD * DD;
        na.bs[0] = A1b + l * DD; na.bs[1] = A2b + l * DD;
        na.bs[2] = B1b + l * DD; na.bs[3] = B2b + l * DD;
        na.bs[4] = C1b + l * DD; na.bs[5] = C2b + l * DD;
        na.out[0] = A1h; na.out[1] = A2h; na.out[2] = B1h;
        na.out[3] = B2h; na.out[4] = C1p; na.out[5] = C2p;
        k_gemmN<<<dim3(NB, 6), 256, 0, stream>>>(na, h16, pf);

        k_zero<<<1, 256, 0, stream>>>(hst, 64);

        if (l == 0) {
            k_zero<<<1, 256, 0, stream>>>(estA, 64);
            k_gemmE<false, true><<<NE / 128, 256, 0, stream>>>(
                e, nullptr, heta, nullptr, nullptr, nullptr,
                WB3, B3b + l * DD, B1h, B2h, ssrc, sdst, estA, 0);
        } else if (l == 1) {
            k_zero<<<1, 256, 0, stream>>>(estB, 64);
            k_gemmE<true, true><<<NE / 128, 256, 0, stream>>>(
                e, heta, heta, estA, bneg + 0 * DD, bneb + 0 * DD,
                WB3, B3b + l * DD, B1h, B2h, ssrc, sdst, estB, 1);
        } else {
            k_gemmE<true, false><<<NE / 128, 256, 0, stream>>>(
                e, heta, heta, estB, bneg + 1 * DD, bneb + 1 * DD,
                WB3, B3b + l * DD, B1h, B2h, ssrc, sdst, nullptr, 0);
        }

        k_agg<<<NN * 16 / 256, 256, 0, stream>>>(heta, A2h, C2p, rowptr, ssrc, snorm,
                                                 A1h, C1p, p, pf, hst,
                                                 (l < NL - 1) ? 1 : 0);

        if (l < NL - 1)
            k_bnupd_h<<<NN * 32 / 256, 256, 0, stream>>>(h, h16, A1h, hst,
                                                         bnhg + l * DD, bnhb + l * DD, 1.0f / NN);
    }

    // ---- readout ----
    k_p16<<<NN * 16 / 256, 256, 0, stream>>>(p, poutW, poutb, p16);
    k_cum<<<1, 64, 0, stream>>>(bnn, cum);
    k_graphstats<<<NG, 256, 0, stream>>>(p16, cum, psum, pss);
    k_final<<<NG, 128, 0, stream>>>(h, A1h, hst, bnhg + (NL - 1) * DD, bnhb + (NL - 1) * DD,
                                    p16, psum, pss, cum,
                                    WhpW, Whpb, W0, b0, W1, b1, W2, b2, out);
}